// Round 1
// baseline (180.197 us; speedup 1.0000x reference)
//
#include <hip/hip_runtime.h>
#include <math.h>

#define NC 100
#define ND 384
#define NB 4096

// ---- kernel 1: per-class prep: wc = 2^w, a = wc*c, tcc[k] = sum_d wc*c*c ----
__global__ __launch_bounds__(ND) void prep_kernel(
    const float* __restrict__ centers, const float* __restrict__ cw,
    float* __restrict__ wc, float* __restrict__ a, float* __restrict__ tcc) {
  int k = blockIdx.x;
  int d = threadIdx.x;  // 384 threads = 6 waves
  float c = centers[k * ND + d];
  float w = exp2f(cw[k * ND + d]);
  wc[k * ND + d] = w;
  a[k * ND + d] = w * c;
  float v = w * c * c;
  #pragma unroll
  for (int off = 32; off; off >>= 1) v += __shfl_xor(v, off, 64);
  __shared__ float s[6];
  int wave = d >> 6;
  if ((d & 63) == 0) s[wave] = v;
  __syncthreads();
  if (d == 0) {
    float t = 0.f;
    #pragma unroll
    for (int i = 0; i < 6; i++) t += s[i];
    tcc[k] = t;
  }
}

// ---- kernel 2: zero presence mask + output accumulator (d_out is poisoned) ----
__global__ void zero_kernel(unsigned* __restrict__ mask, float* __restrict__ out) {
  int t = threadIdx.x;
  if (t < 4) mask[t] = 0u;
  if (t == 4) *out = 0.f;
}

// ---- kernel 3: centers_dist[i] = sqrt(min_{j!=i} sum_d wc[i,d]*(c_i-c_j)^2) ----
__global__ __launch_bounds__(128) void cdist_kernel(
    const float* __restrict__ centers, const float* __restrict__ wc,
    float* __restrict__ cdist) {
  int i = blockIdx.x;
  int j = threadIdx.x;  // 128 threads, j<NC active
  float d2 = 1e30f;
  if (j < NC && j != i) {
    float s = 0.f;
    const float* wi = wc + i * ND;
    const float* ci = centers + i * ND;
    const float* cj = centers + j * ND;
    for (int d = 0; d < ND; d++) {
      float df = ci[d] - cj[d];
      s = fmaf(wi[d] * df, df, s);
    }
    d2 = s;
  }
  __shared__ float s[128];
  s[j] = d2;
  __syncthreads();
  for (int off = 64; off; off >>= 1) {
    if (j < off) s[j] = fminf(s[j], s[j + off]);
    __syncthreads();
  }
  if (j == 0) cdist[i] = sqrtf(s[0]);
}

// ---- kernel 4: presence bitmask of classes appearing in the batch ----
__global__ void presence_kernel(const int* __restrict__ targets,
                                unsigned* __restrict__ mask) {
  int i = blockIdx.x * blockDim.x + threadIdx.x;
  if (i < NB) {
    int t = targets[i];
    atomicOr(&mask[t >> 5], 1u << (t & 31));
  }
}

// ---- kernel 5: main — one wave per sample, B x C distance collapse ----
__global__ __launch_bounds__(256) void main_kernel(
    const float* __restrict__ x, const int* __restrict__ targets,
    const float* __restrict__ wc, const float* __restrict__ a,
    const float* __restrict__ tcc, const float* __restrict__ cdist,
    const unsigned* __restrict__ mask, float* __restrict__ out) {
  int wave = threadIdx.x >> 6;
  int lane = threadIdx.x & 63;
  int i = blockIdx.x * 4 + wave;
  int ti = targets[i];

  float x2[6], m2x[6];
  #pragma unroll
  for (int e = 0; e < 6; e++) {
    float v = x[i * ND + lane + 64 * e];
    x2[e] = v * v;
    m2x[e] = -2.f * v;
  }

  float best_an = 1e30f;
  float d_ap = 0.f;
  for (int k = 0; k < NC; k++) {
    const float* wk = wc + k * ND + lane;
    const float* ak = a + k * ND + lane;
    float acc0 = 0.f, acc1 = 0.f;
    #pragma unroll
    for (int e = 0; e < 6; e++) {
      acc0 = fmaf(x2[e], wk[64 * e], acc0);
      acc1 = fmaf(m2x[e], ak[64 * e], acc1);
    }
    float acc = acc0 + acc1;
    #pragma unroll
    for (int off = 32; off; off >>= 1) acc += __shfl_xor(acc, off, 64);
    float d2 = tcc[k] + acc;
    float dist = sqrtf(fmaxf(d2, 1e-12f));
    if (k == ti) {
      d_ap = dist;
    } else if ((mask[k >> 5] >> (k & 31)) & 1u) {
      best_an = fminf(best_an, dist);
    }
  }

  float cc = cdist[ti];
  float per = d_ap + ((best_an >= cc) ? 0.f : cc - best_an);

  __shared__ float s[4];
  if (lane == 0) s[wave] = per;
  __syncthreads();
  if (threadIdx.x == 0) {
    float t = s[0] + s[1] + s[2] + s[3];
    atomicAdd(out, t * (1.0f / NB));
  }
}

extern "C" void kernel_launch(void* const* d_in, const int* in_sizes, int n_in,
                              void* d_out, int out_size, void* d_ws, size_t ws_size,
                              hipStream_t stream) {
  const float* inputs  = (const float*)d_in[0];
  const int*   targets = (const int*)d_in[1];
  // d_in[2] = epoch_number (unused by the reference math)
  const float* centers = (const float*)d_in[3];
  const float* cw      = (const float*)d_in[4];
  float* out = (float*)d_out;

  float* wc    = (float*)d_ws;          // [NC*ND]
  float* a     = wc + NC * ND;          // [NC*ND]
  float* tcc   = a + NC * ND;           // [NC]
  float* cdist = tcc + NC;              // [NC]
  unsigned* mask = (unsigned*)(cdist + NC);  // [4]

  prep_kernel<<<NC, ND, 0, stream>>>(centers, cw, wc, a, tcc);
  zero_kernel<<<1, 64, 0, stream>>>(mask, out);
  cdist_kernel<<<NC, 128, 0, stream>>>(centers, wc, cdist);
  presence_kernel<<<NB / 256, 256, 0, stream>>>(targets, mask);
  main_kernel<<<NB / 4, 256, 0, stream>>>(inputs, targets, wc, a, tcc, cdist,
                                          mask, out);
}